// Round 2
// baseline (1244.107 us; speedup 1.0000x reference)
//
#include <hip/hip_runtime.h>

#define NN 100000
#define NE 3200000
#define DD 128
#define KC 10
#define NITER 10
#define NBK 512
#define NPAIR (NN / 2)

// ---------------- init: cnorm[j] = ||x_j||^2, j<KC ----------------
__global__ void k_init(const float* __restrict__ x, float* __restrict__ cnorm) {
  const int j = blockIdx.x, l = threadIdx.x;  // <<<KC, 64>>>
  const float2 v = ((const float2*)x)[j * 64 + l];
  float s = v.x * v.x + v.y * v.y;
#pragma unroll
  for (int m = 1; m < 64; m <<= 1) s += __shfl_xor(s, m);
  if (l == 0) cnorm[j] = s;
}

// ------------- fused assign + partial segment-sum -------------
// half-wave (32 lanes) per node; lane hl covers cols 4hl..4hl+3.
__global__ __launch_bounds__(256) void k_iter(
    const float* __restrict__ x, const float* __restrict__ csrc,
    const float* __restrict__ cnorm, float* __restrict__ partial,
    float* __restrict__ cntpart, unsigned char* __restrict__ cl8, int last) {
  __shared__ float cs[KC][DD];
  __shared__ float cn[KC];
  __shared__ float wsum[4][KC][DD];
  __shared__ float wcnt[4][KC];
  const int tid = threadIdx.x;
  for (int i = tid; i < KC * DD; i += 256) ((float*)cs)[i] = csrc[i];
  if (tid < KC) cn[tid] = cnorm[tid];
  __syncthreads();
  const int w = tid >> 6, lane = tid & 63, half = lane >> 5, hl = lane & 31;
  float4 acc[KC];
  float cntacc[KC];
#pragma unroll
  for (int j = 0; j < KC; ++j) {
    acc[j] = float4{0.f, 0.f, 0.f, 0.f};
    cntacc[j] = 0.f;
  }
  // hoist centroid fragments to registers (loop-invariant)
  float4 cfrag[KC];
#pragma unroll
  for (int j = 0; j < KC; ++j) cfrag[j] = *(const float4*)&cs[j][hl * 4];
  const int gw = blockIdx.x * 4 + w;  // 0..NBK*4-1
  const float4* __restrict__ x4 = (const float4*)x;
  for (int p = gw; p < NPAIR; p += NBK * 4) {
    const int row = 2 * p + half;
    const float4 v = x4[(size_t)row * (DD / 4) + hl];
    float d[KC];
#pragma unroll
    for (int j = 0; j < KC; ++j)
      d[j] = v.x * cfrag[j].x + v.y * cfrag[j].y + v.z * cfrag[j].z +
             v.w * cfrag[j].w;
#pragma unroll
    for (int m = 1; m < 32; m <<= 1) {
#pragma unroll
      for (int j = 0; j < KC; ++j) d[j] += __shfl_xor(d[j], m);
    }
    int best = 0;
    float bd = cn[0] - 2.f * d[0];
#pragma unroll
    for (int j = 1; j < KC; ++j) {
      const float dj = cn[j] - 2.f * d[j];
      if (dj < bd) { bd = dj; best = j; }
    }
#pragma unroll
    for (int j = 0; j < KC; ++j) {
      const float f = (best == j) ? 1.f : 0.f;
      acc[j].x += f * v.x;
      acc[j].y += f * v.y;
      acc[j].z += f * v.z;
      acc[j].w += f * v.w;
      cntacc[j] += (hl == 0) ? f : 0.f;
    }
    if (last && hl == 0) cl8[row] = (unsigned char)best;
  }
  // combine the two halves (lane ^ 32) and flush half 0 to LDS
#pragma unroll
  for (int j = 0; j < KC; ++j) {
    acc[j].x += __shfl_xor(acc[j].x, 32);
    acc[j].y += __shfl_xor(acc[j].y, 32);
    acc[j].z += __shfl_xor(acc[j].z, 32);
    acc[j].w += __shfl_xor(acc[j].w, 32);
    cntacc[j] += __shfl_xor(cntacc[j], 32);
    if (half == 0) {
      *(float4*)&wsum[w][j][hl * 4] = acc[j];
      if (hl == 0) wcnt[w][j] = cntacc[j];
    }
  }
  __syncthreads();
  const float* wsf = (const float*)wsum;
  for (int i = tid; i < KC * DD; i += 256)
    partial[(size_t)blockIdx.x * (KC * DD) + i] =
        wsf[i] + wsf[KC * DD + i] + wsf[2 * KC * DD + i] + wsf[3 * KC * DD + i];
  if (tid < KC)
    cntpart[blockIdx.x * KC + tid] =
        wcnt[0][tid] + wcnt[1][tid] + wcnt[2][tid] + wcnt[3][tid];
}

// ------------- centroid update -------------
__global__ __launch_bounds__(256) void k_update(
    const float* __restrict__ partial, const float* __restrict__ cntpart,
    float* __restrict__ c, float* __restrict__ cnorm) {
  const int j = blockIdx.x, tid = threadIdx.x;  // <<<KC, 256>>>
  __shared__ float red[256];
  __shared__ float dsh;
  float cf = 0.f;
  for (int b = tid; b < NBK; b += 256) cf += cntpart[b * KC + j];
  red[tid] = cf;
  __syncthreads();
  for (int s = 128; s > 0; s >>= 1) {
    if (tid < s) red[tid] += red[tid + s];
    __syncthreads();
  }
  if (tid == 0) dsh = fmaxf(red[0], 1.f);
  __syncthreads();
  const float denom = dsh;
  __syncthreads();
  const int k = tid & 127, h = tid >> 7;
  float s0 = 0.f;
  for (int b = h * (NBK / 2); b < (h + 1) * (NBK / 2); ++b)
    s0 += partial[(size_t)b * (KC * DD) + j * DD + k];
  red[tid] = s0;
  __syncthreads();
  if (tid < DD) {
    const float cj = (red[tid] + red[tid + 128]) / denom;
    c[j * DD + tid] = cj;
    red[tid] = cj * cj;
  }
  __syncthreads();
  for (int s = 64; s > 0; s >>= 1) {
    if (tid < s) red[tid] += red[tid + s];
    __syncthreads();
  }
  if (tid == 0) cnorm[j] = red[0];
}

// ------------- centroid attention (10x10) -------------
__global__ __launch_bounds__(DD) void k_ca(const float* __restrict__ c,
                                           const float* __restrict__ WQ,
                                           const float* __restrict__ WV,
                                           float* __restrict__ CA) {
  __shared__ float cs[KC][DD], q[KC][DD], v[KC][DD], pr[KC][KC];
  const int k = threadIdx.x;  // <<<1, DD>>>
  for (int i = 0; i < KC; ++i) cs[i][k] = c[i * DD + k];
  __syncthreads();
  for (int i = 0; i < KC; ++i) {
    float aq = 0.f, av = 0.f;
    for (int m = 0; m < DD; ++m) {
      const float cm = cs[i][m];
      aq += cm * WQ[m * DD + k];
      av += cm * WV[m * DD + k];
    }
    q[i][k] = aq;
    v[i][k] = av;
  }
  __syncthreads();
  if (k < KC * KC) {
    const int i = k / KC, l = k % KC;
    float acc = 0.f;
    for (int m = 0; m < DD; ++m) acc += q[i][m] * v[l][m];
    pr[i][l] = acc / sqrtf((float)DD);
  }
  __syncthreads();
  if (k < KC) {
    float mx = pr[k][0];
    for (int l = 1; l < KC; ++l) mx = fmaxf(mx, pr[k][l]);
    float e[KC];
    float s = 0.f;
    for (int l = 0; l < KC; ++l) {
      e[l] = expf(pr[k][l] - mx);
      s += e[l];
    }
    for (int l = 0; l < KC; ++l) CA[k * KC + l] = e[l] / s;
  }
}

// ------------- edge histogram + per-node table + gather -------------
__global__ __launch_bounds__(256) void k_cnt(const int* __restrict__ e0,
                                             const int* __restrict__ e1,
                                             const unsigned char* __restrict__ cl8,
                                             int* __restrict__ cnt) {
  const int i = blockIdx.x * 256 + threadIdx.x;  // i in [0, NE/4)
  const int4 a = ((const int4*)e0)[i];
  const int4 b = ((const int4*)e1)[i];
  atomicAdd(&cnt[(size_t)a.x * KC + cl8[b.x]], 1);
  atomicAdd(&cnt[(size_t)a.y * KC + cl8[b.y]], 1);
  atomicAdd(&cnt[(size_t)a.z * KC + cl8[b.z]], 1);
  atomicAdd(&cnt[(size_t)a.w * KC + cl8[b.w]], 1);
}

__global__ __launch_bounds__(256) void k_tab(const unsigned char* __restrict__ cl8,
                                             const int* __restrict__ cnt,
                                             const float* __restrict__ CA,
                                             float* __restrict__ tab) {
  __shared__ float cas[KC * KC];
  if (threadIdx.x < KC * KC) cas[threadIdx.x] = CA[threadIdx.x];
  __syncthreads();
  const int n = blockIdx.x * 256 + threadIdx.x;
  if (n >= NN) return;
  const int s = cl8[n];
  const float* car = &cas[s * KC];
  int cj[KC];
#pragma unroll
  for (int j = 0; j < KC; ++j) cj[j] = cnt[(size_t)n * KC + j];
  float m = -INFINITY;
#pragma unroll
  for (int j = 0; j < KC; ++j)
    if (cj[j] > 0) m = fmaxf(m, car[j]);
  if (m == -INFINITY) {
#pragma unroll
    for (int j = 0; j < KC; ++j) tab[(size_t)n * KC + j] = 0.f;
    return;
  }
  float sum = 0.f;
#pragma unroll
  for (int j = 0; j < KC; ++j)
    if (cj[j] > 0) sum += (float)cj[j] * expf(car[j] - m);
  const float den = sum + 1e-16f;
#pragma unroll
  for (int j = 0; j < KC; ++j) tab[(size_t)n * KC + j] = expf(car[j] - m) / den;
}

__global__ __launch_bounds__(256) void k_gather(const int* __restrict__ e0,
                                                const int* __restrict__ e1,
                                                const unsigned char* __restrict__ cl8,
                                                const float* __restrict__ tab,
                                                float* __restrict__ out) {
  const int i = blockIdx.x * 256 + threadIdx.x;  // i in [0, NE/4)
  const int4 a = ((const int4*)e0)[i];
  const int4 b = ((const int4*)e1)[i];
  float4 r;
  r.x = tab[(size_t)a.x * KC + cl8[b.x]];
  r.y = tab[(size_t)a.y * KC + cl8[b.y]];
  r.z = tab[(size_t)a.z * KC + cl8[b.z]];
  r.w = tab[(size_t)a.w * KC + cl8[b.w]];
  ((float4*)out)[i] = r;
}

// ---------------- launch ----------------
extern "C" void kernel_launch(void* const* d_in, const int* in_sizes, int n_in,
                              void* d_out, int out_size, void* d_ws,
                              size_t ws_size, hipStream_t stream) {
  const float* x = (const float*)d_in[0];
  const int* edge = (const int*)d_in[1];
  const float* WQ = (const float*)d_in[2];
  const float* WV = (const float*)d_in[3];
  float* out = (float*)d_out;
  const int* e0 = edge;
  const int* e1 = edge + NE;

  float* ws = (float*)d_ws;
  float* c = ws;                                  // 1280
  float* cnorm = ws + 1280;                       // 16 (pad)
  float* CA = ws + 1296;                          // 112 (pad)
  float* partial = ws + 1408;                     // NBK*KC*DD = 655360
  float* cntpart = partial + (size_t)NBK * KC * DD;  // NBK*KC = 5120
  float* tab = cntpart + NBK * KC;                // NN*KC = 1,000,000
  int* cnt = (int*)(tab + (size_t)NN * KC);       // NN*KC ints
  unsigned char* cl8 = (unsigned char*)(cnt + (size_t)NN * KC);  // NN bytes
  // total ~10.7 MB

  hipMemsetAsync(cnt, 0, (size_t)NN * KC * sizeof(int), stream);

  k_init<<<KC, 64, 0, stream>>>(x, cnorm);
  for (int it = 0; it < NITER; ++it) {
    const float* csrc = (it == 0) ? x : c;
    k_iter<<<NBK, 256, 0, stream>>>(x, csrc, cnorm, partial, cntpart, cl8,
                                    it == NITER - 1);
    k_update<<<KC, 256, 0, stream>>>(partial, cntpart, c, cnorm);
  }
  k_ca<<<1, DD, 0, stream>>>(c, WQ, WV, CA);
  k_cnt<<<NE / 4 / 256, 256, 0, stream>>>(e0, e1, cl8, cnt);
  k_tab<<<(NN + 255) / 256, 256, 0, stream>>>(cl8, cnt, CA, tab);
  k_gather<<<NE / 4 / 256, 256, 0, stream>>>(e0, e1, cl8, tab, out);
}